// Round 1
// baseline (492.414 us; speedup 1.0000x reference)
//
#include <hip/hip_runtime.h>
#include <math.h>

#define N_REAL 2800
#define NPAD   3000
#define F_IN   8192
#define H1     256
#define H2     128
#define NE     179200
#define UDIM   512   // H1 + H2 + H2
#define NGATE  512   // 4*H2

// ---------------- GEMM1: C(3000x256) += x(2800x8192 padded) @ fc0_w(8192x256), split-K atomic ----------------
__global__ __launch_bounds__(256)
void gemm1_splitk(const float* __restrict__ x, const float* __restrict__ w,
                  float* __restrict__ C) {
    __shared__ float As[16][68];
    __shared__ float Bs[16][68];
    const int t  = threadIdx.x;
    const int tx = t & 15, ty = t >> 4;
    const int n0 = blockIdx.x * 64;
    const int m0 = blockIdx.y * 64;
    const int k0 = blockIdx.z * 2048;

    const int aRow = t >> 2;        // 0..63
    const int aK   = (t & 3) * 4;   // 0,4,8,12
    const int bK   = t >> 4;        // 0..15
    const int bN   = (t & 15) * 4;  // 0..60

    const int arow_g = m0 + aRow;
    const float* xrow = (arow_g < N_REAL) ? (x + (size_t)arow_g * F_IN) : nullptr;

    float acc[4][4] = {};
    for (int kk = k0; kk < k0 + 2048; kk += 16) {
        float4 a4 = make_float4(0.f, 0.f, 0.f, 0.f);
        if (xrow) a4 = *(const float4*)(xrow + kk + aK);
        float4 b4 = *(const float4*)(w + (size_t)(kk + bK) * H1 + n0 + bN);
        As[aK + 0][aRow] = a4.x;
        As[aK + 1][aRow] = a4.y;
        As[aK + 2][aRow] = a4.z;
        As[aK + 3][aRow] = a4.w;
        *(float4*)&Bs[bK][bN] = b4;
        __syncthreads();
#pragma unroll
        for (int k = 0; k < 16; k++) {
            float4 av = *(const float4*)&As[k][ty * 4];
            float4 bv = *(const float4*)&Bs[k][tx * 4];
            acc[0][0] += av.x * bv.x; acc[0][1] += av.x * bv.y; acc[0][2] += av.x * bv.z; acc[0][3] += av.x * bv.w;
            acc[1][0] += av.y * bv.x; acc[1][1] += av.y * bv.y; acc[1][2] += av.y * bv.z; acc[1][3] += av.y * bv.w;
            acc[2][0] += av.z * bv.x; acc[2][1] += av.z * bv.y; acc[2][2] += av.z * bv.z; acc[2][3] += av.z * bv.w;
            acc[3][0] += av.w * bv.x; acc[3][1] += av.w * bv.y; acc[3][2] += av.w * bv.z; acc[3][3] += av.w * bv.w;
        }
        __syncthreads();
    }
#pragma unroll
    for (int i = 0; i < 4; i++) {
        int m = m0 + ty * 4 + i;
        if (m < NPAD) {
#pragma unroll
            for (int j = 0; j < 4; j++)
                atomicAdd(&C[(size_t)m * H1 + n0 + tx * 4 + j], acc[i][j]);
        }
    }
}

// ---------------- GEMM2: gates(3000x512) = U(3000x512) @ Wcomb(512x512) + biasv ----------------
__global__ __launch_bounds__(256)
void gemm2_kernel(const float* __restrict__ U, const float* __restrict__ W,
                  const float* __restrict__ biasv, float* __restrict__ gates) {
    __shared__ float As[16][68];
    __shared__ float Bs[16][68];
    const int t  = threadIdx.x;
    const int tx = t & 15, ty = t >> 4;
    const int n0 = blockIdx.x * 64;
    const int m0 = blockIdx.y * 64;

    const int aRow = t >> 2;
    const int aK   = (t & 3) * 4;
    const int bK   = t >> 4;
    const int bN   = (t & 15) * 4;

    const int arow_g = m0 + aRow;
    const float* urow = (arow_g < NPAD) ? (U + (size_t)arow_g * UDIM) : nullptr;

    float acc[4][4] = {};
    for (int kk = 0; kk < UDIM; kk += 16) {
        float4 a4 = make_float4(0.f, 0.f, 0.f, 0.f);
        if (urow) a4 = *(const float4*)(urow + kk + aK);
        float4 b4 = *(const float4*)(W + (size_t)(kk + bK) * NGATE + n0 + bN);
        As[aK + 0][aRow] = a4.x;
        As[aK + 1][aRow] = a4.y;
        As[aK + 2][aRow] = a4.z;
        As[aK + 3][aRow] = a4.w;
        *(float4*)&Bs[bK][bN] = b4;
        __syncthreads();
#pragma unroll
        for (int k = 0; k < 16; k++) {
            float4 av = *(const float4*)&As[k][ty * 4];
            float4 bv = *(const float4*)&Bs[k][tx * 4];
            acc[0][0] += av.x * bv.x; acc[0][1] += av.x * bv.y; acc[0][2] += av.x * bv.z; acc[0][3] += av.x * bv.w;
            acc[1][0] += av.y * bv.x; acc[1][1] += av.y * bv.y; acc[1][2] += av.y * bv.z; acc[1][3] += av.y * bv.w;
            acc[2][0] += av.z * bv.x; acc[2][1] += av.z * bv.y; acc[2][2] += av.z * bv.z; acc[2][3] += av.z * bv.w;
            acc[3][0] += av.w * bv.x; acc[3][1] += av.w * bv.y; acc[3][2] += av.w * bv.z; acc[3][3] += av.w * bv.w;
        }
        __syncthreads();
    }
#pragma unroll
    for (int i = 0; i < 4; i++) {
        int m = m0 + ty * 4 + i;
        if (m < NPAD) {
#pragma unroll
            for (int j = 0; j < 4; j++) {
                int n = n0 + tx * 4 + j;
                gates[(size_t)m * NGATE + n] = acc[i][j] + biasv[n];
            }
        }
    }
}

// ---------------- graph: histogram (deg by row, counts by col) ----------------
__global__ void hist_kernel(const int* __restrict__ ei, const float* __restrict__ ew,
                            float* __restrict__ deg, int* __restrict__ counts) {
    int e = blockIdx.x * blockDim.x + threadIdx.x;
    if (e < NE) {
        int r = ei[e];
        int c = ei[NE + e];
        atomicAdd(&deg[r], ew[e]);
        atomicAdd(&counts[c], 1);
    }
}

// ---------------- exclusive scan over 3000 counts (one block) ----------------
__global__ void scan_kernel(const int* __restrict__ counts, int* __restrict__ offsets) {
    __shared__ int s[1024];
    int t = threadIdx.x;
    int base = 0;
    for (int c = 0; c < 3; c++) {
        int i = c * 1024 + t;
        int v = (i < NPAD) ? counts[i] : 0;
        s[t] = v;
        __syncthreads();
        for (int off = 1; off < 1024; off <<= 1) {
            int add = (t >= off) ? s[t - off] : 0;
            __syncthreads();
            s[t] += add;
            __syncthreads();
        }
        if (i < NPAD) offsets[i] = base + s[t] - v;
        int tot = s[1023];
        __syncthreads();
        base += tot;
    }
    if (t == 0) offsets[NPAD] = base;
}

// ---------------- dinv + cursor init ----------------
__global__ void init_kernel(const float* __restrict__ deg, const int* __restrict__ offsets,
                            float* __restrict__ dinv, int* __restrict__ cursor) {
    int n = blockIdx.x * blockDim.x + threadIdx.x;
    if (n < NPAD) {
        float d = deg[n];
        dinv[n] = (d > 0.f) ? rsqrtf(d) : 0.f;
        cursor[n] = offsets[n];
    }
}

// ---------------- CSR scatter (edge ids grouped by col) ----------------
__global__ void scatter_kernel(const int* __restrict__ ei, int* __restrict__ cursor,
                               int* __restrict__ eid) {
    int e = blockIdx.x * blockDim.x + threadIdx.x;
    if (e < NE) {
        int c = ei[NE + e];
        int p = atomicAdd(&cursor[c], 1);
        eid[p] = e;
    }
}

// ---------------- T1: per-col gather, writes U[:, 384:512] ----------------
__global__ __launch_bounds__(128)
void t1_kernel(const int* __restrict__ ei, const float* __restrict__ ew,
               const float* __restrict__ h0, const float* __restrict__ dinv,
               const int* __restrict__ offsets, const int* __restrict__ eid,
               float* __restrict__ U) {
    __shared__ int   sr[128];
    __shared__ float sw[128];
    int n = blockIdx.x;
    int o = threadIdx.x;
    int beg = offsets[n], end = offsets[n + 1];
    float dc = dinv[n];
    float acc = 0.f;
    for (int base = beg; base < end; base += 128) {
        int j = base + o;
        if (j < end) {
            int e = eid[j];
            int r = ei[e];
            sr[o] = r;
            sw[o] = -dinv[r] * ew[e];
        }
        __syncthreads();
        int cnt = min(128, end - base);
        for (int k = 0; k < cnt; k++)
            acc += sw[k] * h0[(size_t)sr[k] * H2 + o];
        __syncthreads();
    }
    U[(size_t)n * UDIM + H1 + H2 + o] = acc * dc;
}

// ---------------- epilogue: z = relu(C + b) into U[:,0:256]; copy h0 into U[:,256:384] ----------------
__global__ void epi_kernel(const float* __restrict__ C, const float* __restrict__ b,
                           const float* __restrict__ h0, float* __restrict__ U) {
    int idx = blockIdx.x * 256 + threadIdx.x;
    const int total1 = NPAD * H1;
    if (idx < total1) {
        int n = idx >> 8;
        int c = idx & 255;
        float v = C[idx] + b[c];
        U[(size_t)n * UDIM + c] = fmaxf(v, 0.f);
    } else {
        int idx2 = idx - total1;
        if (idx2 < NPAD * H2) {
            int n = idx2 >> 7;
            int o = idx2 & 127;
            U[(size_t)n * UDIM + H1 + o] = h0[idx2];
        }
    }
}

// ---------------- build Wcomb (512x512) + bias vector (512) ----------------
__global__ void wbuild_kernel(const float* __restrict__ Wx, const float* __restrict__ cw0,
                              const float* __restrict__ cw1, const float* __restrict__ bg,
                              const float* __restrict__ cb, float* __restrict__ W,
                              float* __restrict__ biasv) {
    int idx = blockIdx.x * 256 + threadIdx.x;
    if (idx < UDIM * NGATE) {
        int f   = idx >> 9;
        int col = idx & 511;
        int g = col >> 7, o = col & 127;
        float v;
        if (f < H1)            v = Wx[((size_t)g * H1 + f) * H2 + o];
        else if (f < H1 + H2)  v = cw0[((size_t)g * H2 + (f - H1)) * H2 + o];
        else                   v = cw1[((size_t)g * H2 + (f - H1 - H2)) * H2 + o];
        W[idx] = v;
        if (f == 0) biasv[col] = bg[col] + cb[col];
    }
}

// ---------------- LSTM elementwise + output projection ----------------
__global__ __launch_bounds__(128)
void lstm_kernel(const float* __restrict__ gates, const float* __restrict__ c0,
                 const float* __restrict__ fc_w, const float* __restrict__ fc_b,
                 float* __restrict__ out) {
    __shared__ float red[2];
    int n = blockIdx.x;
    int o = threadIdx.x;
    const float* g = gates + (size_t)n * NGATE;
    float gi = g[o];
    float gf = g[H2 + o];
    float gt = g[2 * H2 + o];
    float go = g[3 * H2 + o];
    float iv = 1.f / (1.f + expf(-gi));
    float fv = 1.f / (1.f + expf(-gf));
    float tv = tanhf(gt);
    float ov = 1.f / (1.f + expf(-go));
    float c = fv * c0[(size_t)n * H2 + o] + iv * tv;
    float h = ov * tanhf(c);
    out[N_REAL + (size_t)n * H2 + o] = h;

    float r = fmaxf(h, 0.f) * fc_w[o];
#pragma unroll
    for (int s = 32; s; s >>= 1) r += __shfl_down(r, s);
    if ((o & 63) == 0) red[o >> 6] = r;
    __syncthreads();
    if (o == 0 && n < N_REAL) out[n] = red[0] + red[1] + fc_b[0];
}

extern "C" void kernel_launch(void* const* d_in, const int* in_sizes, int n_in,
                              void* d_out, int out_size, void* d_ws, size_t ws_size,
                              hipStream_t stream) {
    const float* x     = (const float*)d_in[0];
    const int*   ei    = (const int*)d_in[1];
    const float* ew    = (const float*)d_in[2];
    const float* h0    = (const float*)d_in[3];
    const float* c0    = (const float*)d_in[4];
    const float* fc0_w = (const float*)d_in[5];
    const float* fc0_b = (const float*)d_in[6];
    const float* Wx    = (const float*)d_in[7];
    const float* bg    = (const float*)d_in[8];
    const float* cw0   = (const float*)d_in[9];
    const float* cw1   = (const float*)d_in[10];
    const float* cb    = (const float*)d_in[11];
    const float* fc_w  = (const float*)d_in[12];
    const float* fc_b  = (const float*)d_in[13];
    float* out = (float*)d_out;

    float* C      = (float*)d_ws;                 // 3000*256
    float* U      = C + (size_t)NPAD * H1;        // 3000*512
    float* W      = U + (size_t)NPAD * UDIM;      // 512*512
    float* biasv  = W + (size_t)UDIM * NGATE;     // 512
    float* gates  = biasv + NGATE;                // 3000*512
    float* deg    = gates + (size_t)NPAD * NGATE; // 3000
    float* dinv   = deg + NPAD;                   // 3000
    int*   counts = (int*)(dinv + NPAD);          // 3008
    int*   offs   = counts + 3008;                // 3008 (+1 total slot)
    int*   cursor = offs + 3008;                  // 3008
    int*   eid    = cursor + 3008;                // NE

    hipMemsetAsync(C, 0, (size_t)NPAD * H1 * sizeof(float), stream);
    hipMemsetAsync(deg, 0, NPAD * sizeof(float), stream);
    hipMemsetAsync(counts, 0, 3008 * sizeof(int), stream);

    gemm1_splitk<<<dim3(4, 47, 4), 256, 0, stream>>>(x, fc0_w, C);
    hist_kernel<<<(NE + 255) / 256, 256, 0, stream>>>(ei, ew, deg, counts);
    scan_kernel<<<1, 1024, 0, stream>>>(counts, offs);
    init_kernel<<<(NPAD + 255) / 256, 256, 0, stream>>>(deg, offs, dinv, cursor);
    scatter_kernel<<<(NE + 255) / 256, 256, 0, stream>>>(ei, cursor, eid);
    t1_kernel<<<NPAD, 128, 0, stream>>>(ei, ew, h0, dinv, offs, eid, U);
    epi_kernel<<<(NPAD * (H1 + H2) + 255) / 256, 256, 0, stream>>>(C, fc0_b, h0, U);
    wbuild_kernel<<<(UDIM * NGATE + 255) / 256, 256, 0, stream>>>(Wx, cw0, cw1, bg, cb, W, biasv);
    gemm2_kernel<<<dim3(8, 47), 256, 0, stream>>>(U, W, biasv, gates);
    lstm_kernel<<<NPAD, 128, 0, stream>>>(gates, c0, fc_w, fc_b, out);
}

// Round 2
// 362.438 us; speedup vs baseline: 1.3586x; 1.3586x over previous
//
#include <hip/hip_runtime.h>
#include <math.h>

#define N_REAL 2800
#define NPAD   3000
#define F_IN   8192
#define H1     256
#define H2     128
#define NE     179200
#define UDIM   512   // H1 + H2 + H2
#define NGATE  512   // 4*H2
#define MPAD   3072  // 24 * 128

typedef _Float16 half8_t __attribute__((ext_vector_type(8)));
typedef float    floatx4 __attribute__((ext_vector_type(4)));

__device__ __forceinline__ void async_g2l_16(const _Float16* g, _Float16* l) {
    __builtin_amdgcn_global_load_lds(
        (const __attribute__((address_space(1))) unsigned int*)g,
        (__attribute__((address_space(3))) unsigned int*)l, 16, 0, 0);
}

// ---------------- convert x (2800x8192 f32) -> xh (3072x8192 f16, zero-padded rows) ----------------
__global__ __launch_bounds__(256)
void convert_x(const float* __restrict__ x, _Float16* __restrict__ xh) {
    size_t idx = ((size_t)blockIdx.x * 256 + threadIdx.x) * 8;
    int row = (int)(idx >> 13);
    half8_t h = {};
    if (row < N_REAL) {
        const float4* p = (const float4*)(x + idx);
        float4 a = p[0], b = p[1];
        h[0] = (_Float16)a.x; h[1] = (_Float16)a.y; h[2] = (_Float16)a.z; h[3] = (_Float16)a.w;
        h[4] = (_Float16)b.x; h[5] = (_Float16)b.y; h[6] = (_Float16)b.z; h[7] = (_Float16)b.w;
    }
    *(half8_t*)(xh + idx) = h;
}

// ---------------- convert+transpose fc0_w (8192x256 f32) -> wT (256x8192 f16) ----------------
__global__ __launch_bounds__(256)
void convert_w(const float* __restrict__ w, _Float16* __restrict__ wT) {
    __shared__ float tile[32][33];
    int k0 = blockIdx.x * 32;
    int n0 = blockIdx.y * 32;
    int tx = threadIdx.x, ty = threadIdx.y; // 32 x 8
#pragma unroll
    for (int r = 0; r < 4; r++)
        tile[ty + r * 8][tx] = w[(size_t)(k0 + ty + r * 8) * H1 + n0 + tx];
    __syncthreads();
#pragma unroll
    for (int r = 0; r < 4; r++)
        wT[(size_t)(n0 + ty + r * 8) * F_IN + k0 + tx] = (_Float16)tile[tx][ty + r * 8];
}

// ---------------- GEMM1 (MFMA f16): C(3000x256) += xh(3072x8192) @ wT^T, split-K=16 atomic ----------------
__global__ __launch_bounds__(256, 3)
void gemm1_mfma(const _Float16* __restrict__ xh, const _Float16* __restrict__ wT,
                float* __restrict__ C) {
    // LDS layout: [k-unit u (8 f16 = 16B)][row 0..127][8 f16] — contiguous per staging instr,
    // conflict-free-enough for ds_read_b128 (consecutive-lane rows stride 16B = 4 banks).
    __shared__ _Float16 As[4][128][8];
    __shared__ _Float16 Bs[4][128][8];
    const int t    = threadIdx.x;
    const int wave = t >> 6, lane = t & 63;
    const int wr   = wave >> 1, wc = wave & 1;
    const int l16  = lane & 15, u = lane >> 4;
    const int m0 = blockIdx.x * 128;
    const int n0 = blockIdx.y * 128;
    const int k0 = blockIdx.z * 512;

    floatx4 acc[4][4] = {};

    // staging: wave == k-unit; two row-groups (0..63, 64..127) for A and B each
    const _Float16* ga0 = xh + (size_t)(m0 + lane) * F_IN + k0 + wave * 8;
    const _Float16* ga1 = ga0 + (size_t)64 * F_IN;
    const _Float16* gb0 = wT + (size_t)(n0 + lane) * F_IN + k0 + wave * 8;
    const _Float16* gb1 = gb0 + (size_t)64 * F_IN;
    _Float16* la0 = &As[wave][lane][0];
    _Float16* la1 = &As[wave][64 + lane][0];
    _Float16* lb0 = &Bs[wave][lane][0];
    _Float16* lb1 = &Bs[wave][64 + lane][0];

    for (int kk = 0; kk < 512; kk += 32) {
        async_g2l_16(ga0, la0);
        async_g2l_16(ga1, la1);
        async_g2l_16(gb0, lb0);
        async_g2l_16(gb1, lb1);
        ga0 += 32; ga1 += 32; gb0 += 32; gb1 += 32;
        __syncthreads();
        half8_t a[4], b[4];
#pragma unroll
        for (int i = 0; i < 4; i++) a[i] = *(const half8_t*)&As[u][wr * 64 + i * 16 + l16][0];
#pragma unroll
        for (int j = 0; j < 4; j++) b[j] = *(const half8_t*)&Bs[u][wc * 64 + j * 16 + l16][0];
#pragma unroll
        for (int i = 0; i < 4; i++)
#pragma unroll
            for (int j = 0; j < 4; j++)
                acc[i][j] = __builtin_amdgcn_mfma_f32_16x16x32_f16(a[i], b[j], acc[i][j], 0, 0, 0);
        __syncthreads();
    }

#pragma unroll
    for (int i = 0; i < 4; i++) {
        int mB = m0 + wr * 64 + i * 16 + u * 4;
#pragma unroll
        for (int j = 0; j < 4; j++) {
            int n = n0 + wc * 64 + j * 16 + l16;
#pragma unroll
            for (int r = 0; r < 4; r++) {
                int m = mB + r;
                if (m < NPAD) atomicAdd(&C[(size_t)m * H1 + n], acc[i][j][r]);
            }
        }
    }
}

// ---------------- GEMM2: gates(3000x512) = U(3000x512) @ Wcomb(512x512) + biasv ----------------
__global__ __launch_bounds__(256)
void gemm2_kernel(const float* __restrict__ U, const float* __restrict__ W,
                  const float* __restrict__ biasv, float* __restrict__ gates) {
    __shared__ float As[16][68];
    __shared__ float Bs[16][68];
    const int t  = threadIdx.x;
    const int tx = t & 15, ty = t >> 4;
    const int n0 = blockIdx.x * 64;
    const int m0 = blockIdx.y * 64;

    const int aRow = t >> 2;
    const int aK   = (t & 3) * 4;
    const int bK   = t >> 4;
    const int bN   = (t & 15) * 4;

    const int arow_g = m0 + aRow;
    const float* urow = (arow_g < NPAD) ? (U + (size_t)arow_g * UDIM) : nullptr;

    float acc[4][4] = {};
    for (int kk = 0; kk < UDIM; kk += 16) {
        float4 a4 = make_float4(0.f, 0.f, 0.f, 0.f);
        if (urow) a4 = *(const float4*)(urow + kk + aK);
        float4 b4 = *(const float4*)(W + (size_t)(kk + bK) * NGATE + n0 + bN);
        As[aK + 0][aRow] = a4.x;
        As[aK + 1][aRow] = a4.y;
        As[aK + 2][aRow] = a4.z;
        As[aK + 3][aRow] = a4.w;
        *(float4*)&Bs[bK][bN] = b4;
        __syncthreads();
#pragma unroll
        for (int k = 0; k < 16; k++) {
            float4 av = *(const float4*)&As[k][ty * 4];
            float4 bv = *(const float4*)&Bs[k][tx * 4];
            acc[0][0] += av.x * bv.x; acc[0][1] += av.x * bv.y; acc[0][2] += av.x * bv.z; acc[0][3] += av.x * bv.w;
            acc[1][0] += av.y * bv.x; acc[1][1] += av.y * bv.y; acc[1][2] += av.y * bv.z; acc[1][3] += av.y * bv.w;
            acc[2][0] += av.z * bv.x; acc[2][1] += av.z * bv.y; acc[2][2] += av.z * bv.z; acc[2][3] += av.z * bv.w;
            acc[3][0] += av.w * bv.x; acc[3][1] += av.w * bv.y; acc[3][2] += av.w * bv.z; acc[3][3] += av.w * bv.w;
        }
        __syncthreads();
    }
#pragma unroll
    for (int i = 0; i < 4; i++) {
        int m = m0 + ty * 4 + i;
        if (m < NPAD) {
#pragma unroll
            for (int j = 0; j < 4; j++) {
                int n = n0 + tx * 4 + j;
                gates[(size_t)m * NGATE + n] = acc[i][j] + biasv[n];
            }
        }
    }
}

// ---------------- graph: histogram (deg by row, counts by col) ----------------
__global__ void hist_kernel(const int* __restrict__ ei, const float* __restrict__ ew,
                            float* __restrict__ deg, int* __restrict__ counts) {
    int e = blockIdx.x * blockDim.x + threadIdx.x;
    if (e < NE) {
        int r = ei[e];
        int c = ei[NE + e];
        atomicAdd(&deg[r], ew[e]);
        atomicAdd(&counts[c], 1);
    }
}

// ---------------- exclusive scan over 3000 counts (one block) ----------------
__global__ void scan_kernel(const int* __restrict__ counts, int* __restrict__ offsets) {
    __shared__ int s[1024];
    int t = threadIdx.x;
    int base = 0;
    for (int c = 0; c < 3; c++) {
        int i = c * 1024 + t;
        int v = (i < NPAD) ? counts[i] : 0;
        s[t] = v;
        __syncthreads();
        for (int off = 1; off < 1024; off <<= 1) {
            int add = (t >= off) ? s[t - off] : 0;
            __syncthreads();
            s[t] += add;
            __syncthreads();
        }
        if (i < NPAD) offsets[i] = base + s[t] - v;
        int tot = s[1023];
        __syncthreads();
        base += tot;
    }
    if (t == 0) offsets[NPAD] = base;
}

// ---------------- dinv + cursor init ----------------
__global__ void init_kernel(const float* __restrict__ deg, const int* __restrict__ offsets,
                            float* __restrict__ dinv, int* __restrict__ cursor) {
    int n = blockIdx.x * blockDim.x + threadIdx.x;
    if (n < NPAD) {
        float d = deg[n];
        dinv[n] = (d > 0.f) ? rsqrtf(d) : 0.f;
        cursor[n] = offsets[n];
    }
}

// ---------------- CSR scatter (edge ids grouped by col) ----------------
__global__ void scatter_kernel(const int* __restrict__ ei, int* __restrict__ cursor,
                               int* __restrict__ eid) {
    int e = blockIdx.x * blockDim.x + threadIdx.x;
    if (e < NE) {
        int c = ei[NE + e];
        int p = atomicAdd(&cursor[c], 1);
        eid[p] = e;
    }
}

// ---------------- T1: per-col gather, writes U[:, 384:512] ----------------
__global__ __launch_bounds__(128)
void t1_kernel(const int* __restrict__ ei, const float* __restrict__ ew,
               const float* __restrict__ h0, const float* __restrict__ dinv,
               const int* __restrict__ offsets, const int* __restrict__ eid,
               float* __restrict__ U) {
    __shared__ int   sr[128];
    __shared__ float sw[128];
    int n = blockIdx.x;
    int o = threadIdx.x;
    int beg = offsets[n], end = offsets[n + 1];
    float dc = dinv[n];
    float acc = 0.f;
    for (int base = beg; base < end; base += 128) {
        int j = base + o;
        if (j < end) {
            int e = eid[j];
            int r = ei[e];
            sr[o] = r;
            sw[o] = -dinv[r] * ew[e];
        }
        __syncthreads();
        int cnt = min(128, end - base);
        for (int k = 0; k < cnt; k++)
            acc += sw[k] * h0[(size_t)sr[k] * H2 + o];
        __syncthreads();
    }
    U[(size_t)n * UDIM + H1 + H2 + o] = acc * dc;
}

// ---------------- epilogue: z = relu(C + b) into U[:,0:256]; copy h0 into U[:,256:384] ----------------
__global__ void epi_kernel(const float* __restrict__ C, const float* __restrict__ b,
                           const float* __restrict__ h0, float* __restrict__ U) {
    int idx = blockIdx.x * 256 + threadIdx.x;
    const int total1 = NPAD * H1;
    if (idx < total1) {
        int n = idx >> 8;
        int c = idx & 255;
        float v = C[idx] + b[c];
        U[(size_t)n * UDIM + c] = fmaxf(v, 0.f);
    } else {
        int idx2 = idx - total1;
        if (idx2 < NPAD * H2) {
            int n = idx2 >> 7;
            int o = idx2 & 127;
            U[(size_t)n * UDIM + H1 + o] = h0[idx2];
        }
    }
}

// ---------------- build Wcomb (512x512) + bias vector (512) ----------------
__global__ void wbuild_kernel(const float* __restrict__ Wx, const float* __restrict__ cw0,
                              const float* __restrict__ cw1, const float* __restrict__ bg,
                              const float* __restrict__ cb, float* __restrict__ W,
                              float* __restrict__ biasv) {
    int idx = blockIdx.x * 256 + threadIdx.x;
    if (idx < UDIM * NGATE) {
        int f   = idx >> 9;
        int col = idx & 511;
        int g = col >> 7, o = col & 127;
        float v;
        if (f < H1)            v = Wx[((size_t)g * H1 + f) * H2 + o];
        else if (f < H1 + H2)  v = cw0[((size_t)g * H2 + (f - H1)) * H2 + o];
        else                   v = cw1[((size_t)g * H2 + (f - H1 - H2)) * H2 + o];
        W[idx] = v;
        if (f == 0) biasv[col] = bg[col] + cb[col];
    }
}

// ---------------- LSTM elementwise + output projection ----------------
__global__ __launch_bounds__(128)
void lstm_kernel(const float* __restrict__ gates, const float* __restrict__ c0,
                 const float* __restrict__ fc_w, const float* __restrict__ fc_b,
                 float* __restrict__ out) {
    __shared__ float red[2];
    int n = blockIdx.x;
    int o = threadIdx.x;
    const float* g = gates + (size_t)n * NGATE;
    float gi = g[o];
    float gf = g[H2 + o];
    float gt = g[2 * H2 + o];
    float go = g[3 * H2 + o];
    float iv = 1.f / (1.f + expf(-gi));
    float fv = 1.f / (1.f + expf(-gf));
    float tv = tanhf(gt);
    float ov = 1.f / (1.f + expf(-go));
    float c = fv * c0[(size_t)n * H2 + o] + iv * tv;
    float h = ov * tanhf(c);
    out[N_REAL + (size_t)n * H2 + o] = h;

    float r = fmaxf(h, 0.f) * fc_w[o];
#pragma unroll
    for (int s = 32; s; s >>= 1) r += __shfl_down(r, s);
    if ((o & 63) == 0) red[o >> 6] = r;
    __syncthreads();
    if (o == 0 && n < N_REAL) out[n] = red[0] + red[1] + fc_b[0];
}

extern "C" void kernel_launch(void* const* d_in, const int* in_sizes, int n_in,
                              void* d_out, int out_size, void* d_ws, size_t ws_size,
                              hipStream_t stream) {
    const float* x     = (const float*)d_in[0];
    const int*   ei    = (const int*)d_in[1];
    const float* ew    = (const float*)d_in[2];
    const float* h0    = (const float*)d_in[3];
    const float* c0    = (const float*)d_in[4];
    const float* fc0_w = (const float*)d_in[5];
    const float* fc0_b = (const float*)d_in[6];
    const float* Wx    = (const float*)d_in[7];
    const float* bg    = (const float*)d_in[8];
    const float* cw0   = (const float*)d_in[9];
    const float* cw1   = (const float*)d_in[10];
    const float* cb    = (const float*)d_in[11];
    const float* fc_w  = (const float*)d_in[12];
    const float* fc_b  = (const float*)d_in[13];
    float* out = (float*)d_out;

    float* C      = (float*)d_ws;                 // 3000*256
    float* U      = C + (size_t)NPAD * H1;        // 3000*512
    float* W      = U + (size_t)NPAD * UDIM;      // 512*512
    float* biasv  = W + (size_t)UDIM * NGATE;     // 512
    float* gates  = biasv + NGATE;                // 3000*512
    float* deg    = gates + (size_t)NPAD * NGATE; // 3000
    float* dinv   = deg + NPAD;                   // 3000
    int*   counts = (int*)(dinv + NPAD);          // 3008
    int*   offs   = counts + 3008;                // 3008 (+1 total slot)
    int*   cursor = offs + 3008;                  // 3008
    int*   eid    = cursor + 3008;                // NE
    _Float16* xh  = (_Float16*)(((uintptr_t)(eid + NE) + 255) & ~(uintptr_t)255); // 3072*8192 f16
    _Float16* wT  = xh + (size_t)MPAD * F_IN;     // 256*8192 f16

    hipMemsetAsync(C, 0, (size_t)NPAD * H1 * sizeof(float), stream);
    hipMemsetAsync(deg, 0, NPAD * sizeof(float), stream);
    hipMemsetAsync(counts, 0, 3008 * sizeof(int), stream);

    convert_x<<<(MPAD * F_IN / 8 + 255) / 256, 256, 0, stream>>>(x, xh);
    convert_w<<<dim3(F_IN / 32, H1 / 32), dim3(32, 8), 0, stream>>>(fc0_w, wT);
    gemm1_mfma<<<dim3(MPAD / 128, 2, 16), 256, 0, stream>>>(xh, wT, C);

    hist_kernel<<<(NE + 255) / 256, 256, 0, stream>>>(ei, ew, deg, counts);
    scan_kernel<<<1, 1024, 0, stream>>>(counts, offs);
    init_kernel<<<(NPAD + 255) / 256, 256, 0, stream>>>(deg, offs, dinv, cursor);
    scatter_kernel<<<(NE + 255) / 256, 256, 0, stream>>>(ei, cursor, eid);
    t1_kernel<<<NPAD, 128, 0, stream>>>(ei, ew, h0, dinv, offs, eid, U);
    epi_kernel<<<(NPAD * (H1 + H2) + 255) / 256, 256, 0, stream>>>(C, fc0_b, h0, U);
    wbuild_kernel<<<(UDIM * NGATE + 255) / 256, 256, 0, stream>>>(Wx, cw0, cw1, bg, cb, W, biasv);
    gemm2_kernel<<<dim3(8, 47), 256, 0, stream>>>(U, W, biasv, gates);
    lstm_kernel<<<NPAD, 128, 0, stream>>>(gates, c0, fc_w, fc_b, out);
}

// Round 3
// 325.950 us; speedup vs baseline: 1.5107x; 1.1119x over previous
//
#include <hip/hip_runtime.h>
#include <math.h>

#define N_REAL 2800
#define NPAD   3000
#define F_IN   8192
#define H1     256
#define H2     128
#define NE     179200
#define UDIM   512
#define NGATE  512
#define MPAD   3072
#define SPLITK 8
#define KCH    (F_IN / SPLITK)   // 1024

typedef _Float16 half8_t __attribute__((ext_vector_type(8)));
typedef _Float16 half4_t __attribute__((ext_vector_type(4)));
typedef float    floatx4 __attribute__((ext_vector_type(4)));

__device__ __forceinline__ void async_g2l_16(const _Float16* g, _Float16* l) {
    __builtin_amdgcn_global_load_lds(
        (const __attribute__((address_space(1))) unsigned int*)g,
        (__attribute__((address_space(3))) unsigned int*)l, 16, 0, 0);
}

// ---------------- convert+transpose fc0_w (8192x256 f32) -> wT (256x8192 f16) ----------------
__global__ __launch_bounds__(256)
void convert_w(const float* __restrict__ w, _Float16* __restrict__ wT) {
    __shared__ float tile[32][33];
    int k0 = blockIdx.x * 32;
    int n0 = blockIdx.y * 32;
    int tx = threadIdx.x, ty = threadIdx.y; // 32 x 8
#pragma unroll
    for (int r = 0; r < 4; r++)
        tile[ty + r * 8][tx] = w[(size_t)(k0 + ty + r * 8) * H1 + n0 + tx];
    __syncthreads();
#pragma unroll
    for (int r = 0; r < 4; r++)
        wT[(size_t)(n0 + ty + r * 8) * F_IN + k0 + tx] = (_Float16)tile[tx][ty + r * 8];
}

// ---------------- GEMM1: P[sk] = x_tile(f32->f16) @ wT^T, tile 64x256, no atomics ----------------
__global__ __launch_bounds__(256)
void gemm1_fused(const float* __restrict__ x, const _Float16* __restrict__ wT,
                 float* __restrict__ P) {
    __shared__ _Float16 Bs[4][256][8];  // [k-unit][n][8 f16] — global_load_lds layout (no pad)
    __shared__ _Float16 As[4][66][8];   // [k-unit][row][8 f16], padded 64->66 for write banks
    const int t = threadIdx.x;
    const int wave = t >> 6, lane = t & 63;
    const int l16 = lane & 15, u = lane >> 4;
    const int m0 = blockIdx.x * 64;
    const int k0 = blockIdx.y * KCH;

    const int arow = t >> 2;      // 0..63
    const int aseg = t & 3;       // 0..3 (8 f32 each)
    const bool avalid = (m0 + arow) < N_REAL;
    const float* agp = x + (size_t)(m0 + arow) * F_IN + k0 + aseg * 8;

    const _Float16* bgp = wT + (size_t)lane * F_IN + k0 + wave * 8;
    _Float16* bl = &Bs[wave][lane][0];

    floatx4 acc[4][4] = {};

    for (int kk = 0; kk < KCH; kk += 32) {
#pragma unroll
        for (int j = 0; j < 4; j++)
            async_g2l_16(bgp + (size_t)(j * 64) * F_IN + kk, bl + j * 64 * 8);
        float4 a0 = make_float4(0.f, 0.f, 0.f, 0.f), a1 = a0;
        if (avalid) {
            a0 = *(const float4*)(agp + kk);
            a1 = *(const float4*)(agp + kk + 4);
        }
        half8_t ah;
        ah[0] = (_Float16)a0.x; ah[1] = (_Float16)a0.y; ah[2] = (_Float16)a0.z; ah[3] = (_Float16)a0.w;
        ah[4] = (_Float16)a1.x; ah[5] = (_Float16)a1.y; ah[6] = (_Float16)a1.z; ah[7] = (_Float16)a1.w;
        *(half8_t*)&As[aseg][arow][0] = ah;
        __syncthreads();
        half8_t a[4], b[4];
#pragma unroll
        for (int i = 0; i < 4; i++) a[i] = *(const half8_t*)&As[u][i * 16 + l16][0];
#pragma unroll
        for (int j = 0; j < 4; j++) b[j] = *(const half8_t*)&Bs[u][wave * 64 + j * 16 + l16][0];
#pragma unroll
        for (int i = 0; i < 4; i++)
#pragma unroll
            for (int j = 0; j < 4; j++)
                acc[i][j] = __builtin_amdgcn_mfma_f32_16x16x32_f16(a[i], b[j], acc[i][j], 0, 0, 0);
        __syncthreads();
    }

    float* Pb = P + (size_t)blockIdx.y * MPAD * H1 + (size_t)m0 * H1;
#pragma unroll
    for (int i = 0; i < 4; i++) {
#pragma unroll
        for (int j = 0; j < 4; j++) {
            int n = wave * 64 + j * 16 + l16;
#pragma unroll
            for (int r = 0; r < 4; r++) {
                int m = i * 16 + u * 4 + r;
                Pb[(size_t)m * H1 + n] = acc[i][j][r];
            }
        }
    }
}

// ---------------- graph: histogram (deg by row, counts by col) ----------------
__global__ void hist_kernel(const int* __restrict__ ei, const float* __restrict__ ew,
                            float* __restrict__ deg, int* __restrict__ counts) {
    int e = blockIdx.x * blockDim.x + threadIdx.x;
    if (e < NE) {
        int r = ei[e];
        int c = ei[NE + e];
        atomicAdd(&deg[r], ew[e]);
        atomicAdd(&counts[c], 1);
    }
}

// ---------------- exclusive scan + dinv + cursor init (one block) ----------------
__global__ void scan_kernel(const int* __restrict__ counts, int* __restrict__ offsets,
                            const float* __restrict__ deg, float* __restrict__ dinv,
                            int* __restrict__ cursor) {
    __shared__ int s[1024];
    int t = threadIdx.x;
    int base = 0;
    for (int c = 0; c < 3; c++) {
        int i = c * 1024 + t;
        int v = (i < NPAD) ? counts[i] : 0;
        s[t] = v;
        __syncthreads();
        for (int off = 1; off < 1024; off <<= 1) {
            int add = (t >= off) ? s[t - off] : 0;
            __syncthreads();
            s[t] += add;
            __syncthreads();
        }
        if (i < NPAD) offsets[i] = base + s[t] - v;
        int tot = s[1023];
        __syncthreads();
        base += tot;
    }
    if (t == 0) offsets[NPAD] = base;
    __syncthreads();
    for (int i = t; i < NPAD; i += 1024) {
        float d = deg[i];
        dinv[i] = (d > 0.f) ? rsqrtf(d) : 0.f;
        cursor[i] = offsets[i];
    }
}

// ---------------- CSR scatter (edge ids grouped by col) ----------------
__global__ void scatter_kernel(const int* __restrict__ ei, int* __restrict__ cursor,
                               int* __restrict__ eid) {
    int e = blockIdx.x * blockDim.x + threadIdx.x;
    if (e < NE) {
        int c = ei[NE + e];
        int p = atomicAdd(&cursor[c], 1);
        eid[p] = e;
    }
}

// ---------------- T1: per-col gather -> U16/UL16 cols [384,512) ----------------
__global__ __launch_bounds__(128)
void t1_kernel(const int* __restrict__ ei, const float* __restrict__ ew,
               const float* __restrict__ h0, const float* __restrict__ dinv,
               const int* __restrict__ offsets, const int* __restrict__ eid,
               _Float16* __restrict__ U16, _Float16* __restrict__ UL16) {
    __shared__ int   sr[128];
    __shared__ float sw[128];
    int n = blockIdx.x;
    int o = threadIdx.x;
    int beg = offsets[n], end = offsets[n + 1];
    float dc = dinv[n];
    float acc = 0.f;
    for (int base = beg; base < end; base += 128) {
        int j = base + o;
        if (j < end) {
            int e = eid[j];
            int r = ei[e];
            sr[o] = r;
            sw[o] = -dinv[r] * ew[e];
        }
        __syncthreads();
        int cnt = min(128, end - base);
        for (int k = 0; k < cnt; k++)
            acc += sw[k] * h0[(size_t)sr[k] * H2 + o];
        __syncthreads();
    }
    float v = acc * dc;
    _Float16 hi = (_Float16)v;
    _Float16 lo = (_Float16)(v - (float)hi);
    U16 [(size_t)n * UDIM + H1 + H2 + o] = hi;
    UL16[(size_t)n * UDIM + H1 + H2 + o] = lo;
}

// ---------------- epilogue: reduce P + bias + relu -> U16/UL16 z-cols; h0 -> cols [256,384) ----------------
__global__ __launch_bounds__(256)
void epi_kernel(const float* __restrict__ P, const float* __restrict__ fc0_b,
                const float* __restrict__ h0, _Float16* __restrict__ U16,
                _Float16* __restrict__ UL16) {
    const int ZQ = MPAD * (H1 / 4);   // 196608
    const int HQ = NPAD * (H2 / 4);   // 96000
    int tid = blockIdx.x * 256 + threadIdx.x;
    if (tid < ZQ) {
        int m = tid >> 6;
        int n = (tid & 63) * 4;
        float sx = 0.f, sy = 0.f, sz = 0.f, sw = 0.f;
#pragma unroll
        for (int sk = 0; sk < SPLITK; sk++) {
            float4 p = *(const float4*)&P[((size_t)sk * MPAD + m) * H1 + n];
            sx += p.x; sy += p.y; sz += p.z; sw += p.w;
        }
        float4 b = *(const float4*)&fc0_b[n];
        sx = fmaxf(sx + b.x, 0.f); sy = fmaxf(sy + b.y, 0.f);
        sz = fmaxf(sz + b.z, 0.f); sw = fmaxf(sw + b.w, 0.f);
        half4_t hi, lo;
        hi[0] = (_Float16)sx; hi[1] = (_Float16)sy; hi[2] = (_Float16)sz; hi[3] = (_Float16)sw;
        lo[0] = (_Float16)(sx - (float)hi[0]); lo[1] = (_Float16)(sy - (float)hi[1]);
        lo[2] = (_Float16)(sz - (float)hi[2]); lo[3] = (_Float16)(sw - (float)hi[3]);
        *(half4_t*)&U16 [(size_t)m * UDIM + n] = hi;
        *(half4_t*)&UL16[(size_t)m * UDIM + n] = lo;
    } else if (tid < ZQ + HQ) {
        int q = tid - ZQ;
        int m = q >> 5;
        int o = (q & 31) * 4;
        float4 v = *(const float4*)&h0[(size_t)m * H2 + o];
        half4_t hi, lo;
        hi[0] = (_Float16)v.x; hi[1] = (_Float16)v.y; hi[2] = (_Float16)v.z; hi[3] = (_Float16)v.w;
        lo[0] = (_Float16)(v.x - (float)hi[0]); lo[1] = (_Float16)(v.y - (float)hi[1]);
        lo[2] = (_Float16)(v.z - (float)hi[2]); lo[3] = (_Float16)(v.w - (float)hi[3]);
        *(half4_t*)&U16 [(size_t)m * UDIM + H1 + o] = hi;
        *(half4_t*)&UL16[(size_t)m * UDIM + H1 + o] = lo;
    }
}

// ---------------- build Wc (512 cols x 512 f, f16, n-major) + bias vector ----------------
__global__ void wbuild_kernel(const float* __restrict__ Wx, const float* __restrict__ cw0,
                              const float* __restrict__ cw1, const float* __restrict__ bg,
                              const float* __restrict__ cb, _Float16* __restrict__ Wc,
                              float* __restrict__ biasv) {
    int idx = blockIdx.x * 256 + threadIdx.x;
    if (idx < UDIM * NGATE) {
        int col = idx >> 9;   // 0..511 (gate*128+o)
        int f   = idx & 511;  // 0..511
        int g = col >> 7, o = col & 127;
        float v;
        if (f < H1)            v = Wx[((size_t)g * H1 + f) * H2 + o];
        else if (f < H1 + H2)  v = cw0[((size_t)g * H2 + (f - H1)) * H2 + o];
        else                   v = cw1[((size_t)g * H2 + (f - H1 - H2)) * H2 + o];
        Wc[idx] = (_Float16)v;
        if (f == 0) biasv[col] = bg[col] + cb[col];
    }
}

// ---------------- GEMM2 (MFMA f16, hi/lo compensated A): gates = U @ Wc^T + biasv ----------------
__global__ __launch_bounds__(256)
void gemm2_mfma(const _Float16* __restrict__ U16, const _Float16* __restrict__ UL16,
                const _Float16* __restrict__ Wc, const float* __restrict__ biasv,
                float* __restrict__ gates) {
    __shared__ _Float16 As[4][128][8];
    __shared__ _Float16 Al[4][128][8];
    __shared__ _Float16 Bs[4][128][8];
    const int t = threadIdx.x;
    const int wave = t >> 6, lane = t & 63;
    const int wr = wave >> 1, wc = wave & 1;
    const int l16 = lane & 15, u = lane >> 4;
    const int m0 = blockIdx.y * 128;
    const int n0 = blockIdx.x * 128;

    floatx4 acc[4][4] = {};

    const _Float16* ga0 = U16  + (size_t)(m0 + lane) * UDIM + wave * 8;
    const _Float16* ga1 = ga0 + (size_t)64 * UDIM;
    const _Float16* gl0 = UL16 + (size_t)(m0 + lane) * UDIM + wave * 8;
    const _Float16* gl1 = gl0 + (size_t)64 * UDIM;
    const _Float16* gb0 = Wc   + (size_t)(n0 + lane) * UDIM + wave * 8;
    const _Float16* gb1 = gb0 + (size_t)64 * UDIM;
    _Float16* la0 = &As[wave][lane][0];
    _Float16* la1 = &As[wave][64 + lane][0];
    _Float16* ll0 = &Al[wave][lane][0];
    _Float16* ll1 = &Al[wave][64 + lane][0];
    _Float16* lb0 = &Bs[wave][lane][0];
    _Float16* lb1 = &Bs[wave][64 + lane][0];

    for (int kk = 0; kk < UDIM; kk += 32) {
        async_g2l_16(ga0 + kk, la0);
        async_g2l_16(ga1 + kk, la1);
        async_g2l_16(gl0 + kk, ll0);
        async_g2l_16(gl1 + kk, ll1);
        async_g2l_16(gb0 + kk, lb0);
        async_g2l_16(gb1 + kk, lb1);
        __syncthreads();
        half8_t a[4], al[4], b[4];
#pragma unroll
        for (int i = 0; i < 4; i++) {
            a[i]  = *(const half8_t*)&As[u][wr * 64 + i * 16 + l16][0];
            al[i] = *(const half8_t*)&Al[u][wr * 64 + i * 16 + l16][0];
        }
#pragma unroll
        for (int j = 0; j < 4; j++) b[j] = *(const half8_t*)&Bs[u][wc * 64 + j * 16 + l16][0];
#pragma unroll
        for (int i = 0; i < 4; i++)
#pragma unroll
            for (int j = 0; j < 4; j++) {
                acc[i][j] = __builtin_amdgcn_mfma_f32_16x16x32_f16(a[i],  b[j], acc[i][j], 0, 0, 0);
                acc[i][j] = __builtin_amdgcn_mfma_f32_16x16x32_f16(al[i], b[j], acc[i][j], 0, 0, 0);
            }
        __syncthreads();
    }

#pragma unroll
    for (int j = 0; j < 4; j++) {
        int n = n0 + wc * 64 + j * 16 + l16;
        float bn = biasv[n];
#pragma unroll
        for (int i = 0; i < 4; i++) {
            int mB = m0 + wr * 64 + i * 16 + u * 4;
#pragma unroll
            for (int r = 0; r < 4; r++)
                gates[(size_t)(mB + r) * NGATE + n] = acc[i][j][r] + bn;
        }
    }
}

// ---------------- LSTM elementwise + output projection ----------------
__global__ __launch_bounds__(128)
void lstm_kernel(const float* __restrict__ gates, const float* __restrict__ c0,
                 const float* __restrict__ fc_w, const float* __restrict__ fc_b,
                 float* __restrict__ out) {
    __shared__ float red[2];
    int n = blockIdx.x;
    int o = threadIdx.x;
    const float* g = gates + (size_t)n * NGATE;
    float gi = g[o];
    float gf = g[H2 + o];
    float gt = g[2 * H2 + o];
    float go = g[3 * H2 + o];
    float iv = 1.f / (1.f + expf(-gi));
    float fv = 1.f / (1.f + expf(-gf));
    float tv = tanhf(gt);
    float ov = 1.f / (1.f + expf(-go));
    float c = fv * c0[(size_t)n * H2 + o] + iv * tv;
    float h = ov * tanhf(c);
    out[N_REAL + (size_t)n * H2 + o] = h;

    float r = fmaxf(h, 0.f) * fc_w[o];
#pragma unroll
    for (int s = 32; s; s >>= 1) r += __shfl_down(r, s);
    if ((o & 63) == 0) red[o >> 6] = r;
    __syncthreads();
    if (o == 0 && n < N_REAL) out[n] = red[0] + red[1] + fc_b[0];
}

extern "C" void kernel_launch(void* const* d_in, const int* in_sizes, int n_in,
                              void* d_out, int out_size, void* d_ws, size_t ws_size,
                              hipStream_t stream) {
    const float* x     = (const float*)d_in[0];
    const int*   ei    = (const int*)d_in[1];
    const float* ew    = (const float*)d_in[2];
    const float* h0    = (const float*)d_in[3];
    const float* c0    = (const float*)d_in[4];
    const float* fc0_w = (const float*)d_in[5];
    const float* fc0_b = (const float*)d_in[6];
    const float* Wx    = (const float*)d_in[7];
    const float* bg    = (const float*)d_in[8];
    const float* cw0   = (const float*)d_in[9];
    const float* cw1   = (const float*)d_in[10];
    const float* cb    = (const float*)d_in[11];
    const float* fc_w  = (const float*)d_in[12];
    const float* fc_b  = (const float*)d_in[13];
    float* out = (float*)d_out;

    float* P      = (float*)d_ws;                     // 8*3072*256
    float* gates  = P + (size_t)SPLITK * MPAD * H1;   // 3072*512
    float* biasv  = gates + (size_t)MPAD * NGATE;     // 512
    float* deg    = biasv + NGATE;                    // 3000
    float* dinv   = deg + NPAD;                       // 3000
    int*   counts = (int*)(dinv + NPAD);              // 3072
    int*   offs   = counts + 3072;                    // 3072 (need 3001)
    int*   cursor = offs + 3072;                      // 3072
    int*   eid    = cursor + 3072;                    // NE
    _Float16* U16  = (_Float16*)(((uintptr_t)(eid + NE) + 255) & ~(uintptr_t)255); // 3072*512
    _Float16* UL16 = U16 + (size_t)MPAD * UDIM;       // 3072*512
    _Float16* Wc   = UL16 + (size_t)MPAD * UDIM;      // 512*512
    _Float16* wT   = Wc + (size_t)UDIM * NGATE;       // 256*8192

    hipMemsetAsync(deg, 0, NPAD * sizeof(float), stream);
    hipMemsetAsync(counts, 0, 3072 * sizeof(int), stream);

    convert_w<<<dim3(F_IN / 32, H1 / 32), dim3(32, 8), 0, stream>>>(fc0_w, wT);
    gemm1_fused<<<dim3(MPAD / 64, SPLITK), 256, 0, stream>>>(x, wT, P);

    hist_kernel<<<(NE + 255) / 256, 256, 0, stream>>>(ei, ew, deg, counts);
    scan_kernel<<<1, 1024, 0, stream>>>(counts, offs, deg, dinv, cursor);
    scatter_kernel<<<(NE + 255) / 256, 256, 0, stream>>>(ei, cursor, eid);
    t1_kernel<<<NPAD, 128, 0, stream>>>(ei, ew, h0, dinv, offs, eid, U16, UL16);
    epi_kernel<<<(MPAD * (H1 / 4) + NPAD * (H2 / 4) + 255) / 256, 256, 0, stream>>>(P, fc0_b, h0, U16, UL16);
    wbuild_kernel<<<(UDIM * NGATE + 255) / 256, 256, 0, stream>>>(Wx, cw0, cw1, bg, cb, Wc, biasv);
    gemm2_mfma<<<dim3(NGATE / 128, MPAD / 128), 256, 0, stream>>>(U16, UL16, Wc, biasv, gates);
    lstm_kernel<<<NPAD, 128, 0, stream>>>(gates, c0, fc_w, fc_b, out);
}

// Round 4
// 295.694 us; speedup vs baseline: 1.6653x; 1.1023x over previous
//
#include <hip/hip_runtime.h>
#include <math.h>

#define N_REAL 2800
#define NPAD   3000
#define F_IN   8192
#define H1     256
#define H2     128
#define NE     179200
#define UDIM   512
#define NGATE  512
#define MPAD   3072
#define SPLITK 16
#define KCH    (F_IN / SPLITK)   // 512

typedef _Float16 half8_t __attribute__((ext_vector_type(8)));
typedef _Float16 half4_t __attribute__((ext_vector_type(4)));
typedef float    floatx4 __attribute__((ext_vector_type(4)));

__device__ __forceinline__ void async_g2l_16(const _Float16* g, _Float16* l) {
    __builtin_amdgcn_global_load_lds(
        (const __attribute__((address_space(1))) unsigned int*)g,
        (__attribute__((address_space(3))) unsigned int*)l, 16, 0, 0);
}

// ---------------- prep: convert+transpose fc0_w -> wT (256x8192 f16)  AND  build Wc + biasv ----------------
__global__ __launch_bounds__(256)
void prep_kernel(const float* __restrict__ w, const float* __restrict__ Wx,
                 const float* __restrict__ cw0, const float* __restrict__ cw1,
                 const float* __restrict__ bg, const float* __restrict__ cb,
                 _Float16* __restrict__ wT, _Float16* __restrict__ Wc,
                 float* __restrict__ biasv) {
    int b = blockIdx.x;
    if (b < 2048) {
        __shared__ float tile[32][33];
        int k0 = (b & 255) * 32;
        int n0 = (b >> 8) * 32;
        int tx = threadIdx.x & 31, ty = threadIdx.x >> 5; // 32 x 8
#pragma unroll
        for (int r = 0; r < 4; r++)
            tile[ty + r * 8][tx] = w[(size_t)(k0 + ty + r * 8) * H1 + n0 + tx];
        __syncthreads();
#pragma unroll
        for (int r = 0; r < 4; r++)
            wT[(size_t)(n0 + ty + r * 8) * F_IN + k0 + tx] = (_Float16)tile[tx][ty + r * 8];
    } else {
        int idx = (b - 2048) * 256 + threadIdx.x;
        if (idx < UDIM * NGATE) {
            int col = idx >> 9;   // gate*128+o
            int f   = idx & 511;
            int g = col >> 7, o = col & 127;
            float v;
            if (f < H1)            v = Wx[((size_t)g * H1 + f) * H2 + o];
            else if (f < H1 + H2)  v = cw0[((size_t)g * H2 + (f - H1)) * H2 + o];
            else                   v = cw1[((size_t)g * H2 + (f - H1 - H2)) * H2 + o];
            Wc[idx] = (_Float16)v;
            if (f == 0) biasv[col] = bg[col] + cb[col];
        }
    }
}

// ---------------- GEMM1: P[sk] = x(f32->f16) @ wT^T, tile 64x256, K=64/iter, 768 blocks ----------------
__global__ __launch_bounds__(256, 3)
void gemm1_fused(const float* __restrict__ x, const _Float16* __restrict__ wT,
                 float* __restrict__ P) {
    __shared__ __align__(16) _Float16 As[8][64][8];   // 8 KB
    __shared__ __align__(16) _Float16 Bs[8][256][8];  // 32 KB
    const int t = threadIdx.x;
    const int wave = t >> 6, lane = t & 63;
    const int l16 = lane & 15, u4 = lane >> 4;
    const int m0 = blockIdx.x * 64;
    const int kbase = blockIdx.y * KCH;

    const int arow = t >> 2;      // 0..63
    const int aseg = t & 3;       // 0..3 (16 f32 each)
    const bool avalid = (m0 + arow) < N_REAL;
    const float* agp = x + (size_t)(m0 + arow) * F_IN + kbase + aseg * 16;

    floatx4 acc[4][4] = {};

    for (int kk = 0; kk < KCH; kk += 64) {
        // B: wave handles k-units {2*wave, 2*wave+1} x 4 row-groups
#pragma unroll
        for (int q = 0; q < 2; q++) {
            int u = wave * 2 + q;
            const _Float16* bsrc = wT + kbase + kk + u * 8;
#pragma unroll
            for (int rg = 0; rg < 4; rg++)
                async_g2l_16(bsrc + (size_t)(rg * 64 + lane) * F_IN, &Bs[u][rg * 64 + lane][0]);
        }
        // A: 16 f32 per thread -> 2 half8 LDS writes
        float4 a0 = make_float4(0.f, 0.f, 0.f, 0.f), a1 = a0, a2 = a0, a3 = a0;
        if (avalid) {
            a0 = *(const float4*)(agp + kk);
            a1 = *(const float4*)(agp + kk + 4);
            a2 = *(const float4*)(agp + kk + 8);
            a3 = *(const float4*)(agp + kk + 12);
        }
        half8_t hlo, hhi;
        hlo[0] = (_Float16)a0.x; hlo[1] = (_Float16)a0.y; hlo[2] = (_Float16)a0.z; hlo[3] = (_Float16)a0.w;
        hlo[4] = (_Float16)a1.x; hlo[5] = (_Float16)a1.y; hlo[6] = (_Float16)a1.z; hlo[7] = (_Float16)a1.w;
        hhi[0] = (_Float16)a2.x; hhi[1] = (_Float16)a2.y; hhi[2] = (_Float16)a2.z; hhi[3] = (_Float16)a2.w;
        hhi[4] = (_Float16)a3.x; hhi[5] = (_Float16)a3.y; hhi[6] = (_Float16)a3.z; hhi[7] = (_Float16)a3.w;
        *(half8_t*)&As[aseg * 2][arow][0]     = hlo;
        *(half8_t*)&As[aseg * 2 + 1][arow][0] = hhi;
        __syncthreads();
#pragma unroll
        for (int ks = 0; ks < 2; ks++) {
            half8_t a[4], b[4];
#pragma unroll
            for (int i = 0; i < 4; i++) a[i] = *(const half8_t*)&As[ks * 4 + u4][i * 16 + l16][0];
#pragma unroll
            for (int j = 0; j < 4; j++) b[j] = *(const half8_t*)&Bs[ks * 4 + u4][wave * 64 + j * 16 + l16][0];
#pragma unroll
            for (int i = 0; i < 4; i++)
#pragma unroll
                for (int j = 0; j < 4; j++)
                    acc[i][j] = __builtin_amdgcn_mfma_f32_16x16x32_f16(a[i], b[j], acc[i][j], 0, 0, 0);
        }
        __syncthreads();
    }

    float* Pb = P + ((size_t)blockIdx.y * MPAD + m0) * H1;
#pragma unroll
    for (int i = 0; i < 4; i++)
#pragma unroll
        for (int j = 0; j < 4; j++) {
            int n = wave * 64 + j * 16 + l16;
#pragma unroll
            for (int r = 0; r < 4; r++)
                Pb[(size_t)(i * 16 + u4 * 4 + r) * H1 + n] = acc[i][j][r];
        }
}

// ---------------- graph: histogram ----------------
__global__ void hist_kernel(const int* __restrict__ ei, const float* __restrict__ ew,
                            float* __restrict__ deg, int* __restrict__ counts) {
    int e = blockIdx.x * blockDim.x + threadIdx.x;
    if (e < NE) {
        int r = ei[e];
        int c = ei[NE + e];
        atomicAdd(&deg[r], ew[e]);
        atomicAdd(&counts[c], 1);
    }
}

// ---------------- scan: shfl-based exclusive scan + dinv + cursor (1 block, 1024 thr, 3 vals/thr) ----------------
__global__ __launch_bounds__(1024)
void scan_kernel(const int* __restrict__ counts, int* __restrict__ offsets,
                 const float* __restrict__ deg, float* __restrict__ dinv,
                 int* __restrict__ cursor) {
    __shared__ int wt[16];
    int t = threadIdx.x;
    int i0 = t * 3;
    int v0 = (i0     < NPAD) ? counts[i0]     : 0;
    int v1 = (i0 + 1 < NPAD) ? counts[i0 + 1] : 0;
    int v2 = (i0 + 2 < NPAD) ? counts[i0 + 2] : 0;
    int s = v0 + v1 + v2;
    int incl = s;
#pragma unroll
    for (int d = 1; d < 64; d <<= 1) {
        int n = __shfl_up(incl, d);
        if ((t & 63) >= d) incl += n;
    }
    if ((t & 63) == 63) wt[t >> 6] = incl;
    __syncthreads();
    if (t < 64) {
        int w = (t < 16) ? wt[t] : 0;
        int wi = w;
#pragma unroll
        for (int d = 1; d < 16; d <<= 1) {
            int n = __shfl_up(wi, d);
            if (t >= d) wi += n;
        }
        if (t < 16) wt[t] = wi - w;   // exclusive wave base
    }
    __syncthreads();
    int base = wt[t >> 6] + (incl - s);
    if (i0 <= NPAD)     { offsets[i0] = base;              if (i0     < NPAD) cursor[i0]     = base; }
    if (i0 + 1 <= NPAD) { offsets[i0 + 1] = base + v0;     if (i0 + 1 < NPAD) cursor[i0 + 1] = base + v0; }
    if (i0 + 2 <= NPAD) { offsets[i0 + 2] = base + v0 + v1; if (i0 + 2 < NPAD) cursor[i0 + 2] = base + v0 + v1; }
    for (int i = t; i < NPAD; i += 1024) {
        float d = deg[i];
        dinv[i] = (d > 0.f) ? rsqrtf(d) : 0.f;
    }
}

// ---------------- CSR scatter ----------------
__global__ void scatter_kernel(const int* __restrict__ ei, int* __restrict__ cursor,
                               int* __restrict__ eid) {
    int e = blockIdx.x * blockDim.x + threadIdx.x;
    if (e < NE) {
        int c = ei[NE + e];
        int p = atomicAdd(&cursor[c], 1);
        eid[p] = e;
    }
}

// ---------------- fused: T1 gather | P-reduce+relu->z | h0 copy  -> U16 ----------------
#define ZBLK 1536   // 3072 rows * 64 float4 / 128 thr
#define HBLK 768    // 3072 rows * 32 half4 / 128 thr
__global__ __launch_bounds__(128)
void t1epi_kernel(const int* __restrict__ ei, const float* __restrict__ ew,
                  const float* __restrict__ h0, const float* __restrict__ dinv,
                  const int* __restrict__ offsets, const int* __restrict__ eid,
                  const float* __restrict__ P, const float* __restrict__ fc0_b,
                  _Float16* __restrict__ U16) {
    int b = blockIdx.x;
    int t = threadIdx.x;
    if (b < NPAD) {
        __shared__ int   sr[128];
        __shared__ float sw[128];
        int n = b;
        int beg = offsets[n], end = offsets[n + 1];
        float dc = dinv[n];
        float acc = 0.f;
        for (int base = beg; base < end; base += 128) {
            int j = base + t;
            if (j < end) {
                int e = eid[j];
                int r = ei[e];
                sr[t] = r;
                sw[t] = -dinv[r] * ew[e];
            }
            __syncthreads();
            int cnt = min(128, end - base);
            for (int k = 0; k < cnt; k++)
                acc += sw[k] * h0[(size_t)sr[k] * H2 + t];
            __syncthreads();
        }
        U16[(size_t)n * UDIM + H1 + H2 + t] = (_Float16)(acc * dc);
    } else if (b < NPAD + ZBLK) {
        int q = (b - NPAD) * 128 + t;
        int m = q >> 6;
        int n4 = (q & 63) * 4;
        float sx = 0.f, sy = 0.f, sz = 0.f, sw = 0.f;
#pragma unroll
        for (int sk = 0; sk < SPLITK; sk++) {
            float4 p = *(const float4*)&P[((size_t)sk * MPAD + m) * H1 + n4];
            sx += p.x; sy += p.y; sz += p.z; sw += p.w;
        }
        float4 bb = *(const float4*)&fc0_b[n4];
        half4_t h;
        h[0] = (_Float16)fmaxf(sx + bb.x, 0.f);
        h[1] = (_Float16)fmaxf(sy + bb.y, 0.f);
        h[2] = (_Float16)fmaxf(sz + bb.z, 0.f);
        h[3] = (_Float16)fmaxf(sw + bb.w, 0.f);
        *(half4_t*)&U16[(size_t)m * UDIM + n4] = h;
    } else {
        int q = (b - NPAD - ZBLK) * 128 + t;
        int m = q >> 5;
        int o4 = (q & 31) * 4;
        half4_t h = {};
        if (m < NPAD) {
            float4 v = *(const float4*)&h0[(size_t)m * H2 + o4];
            h[0] = (_Float16)v.x; h[1] = (_Float16)v.y; h[2] = (_Float16)v.z; h[3] = (_Float16)v.w;
        }
        *(half4_t*)&U16[(size_t)m * UDIM + H1 + o4] = h;
    }
}

// ---------------- GEMM2 (MFMA f16): gates = U16 @ Wc^T (bias added in lstm) ----------------
__global__ __launch_bounds__(256, 3)
void gemm2_mfma(const _Float16* __restrict__ U16, const _Float16* __restrict__ Wc,
                float* __restrict__ gates) {
    __shared__ __align__(16) _Float16 As[8][64][8];
    __shared__ __align__(16) _Float16 Bs[8][256][8];
    const int t = threadIdx.x;
    const int wave = t >> 6, lane = t & 63;
    const int l16 = lane & 15, u4 = lane >> 4;
    const int n0 = blockIdx.x * 256;
    const int m0 = blockIdx.y * 64;

    floatx4 acc[4][4] = {};

    for (int kk = 0; kk < UDIM; kk += 64) {
#pragma unroll
        for (int q = 0; q < 2; q++) {
            int u = wave * 2 + q;
            async_g2l_16(U16 + (size_t)(m0 + lane) * UDIM + kk + u * 8, &As[u][lane][0]);
            const _Float16* bsrc = Wc + kk + u * 8;
#pragma unroll
            for (int rg = 0; rg < 4; rg++)
                async_g2l_16(bsrc + (size_t)(n0 + rg * 64 + lane) * UDIM, &Bs[u][rg * 64 + lane][0]);
        }
        __syncthreads();
#pragma unroll
        for (int ks = 0; ks < 2; ks++) {
            half8_t a[4], b[4];
#pragma unroll
            for (int i = 0; i < 4; i++) a[i] = *(const half8_t*)&As[ks * 4 + u4][i * 16 + l16][0];
#pragma unroll
            for (int j = 0; j < 4; j++) b[j] = *(const half8_t*)&Bs[ks * 4 + u4][wave * 64 + j * 16 + l16][0];
#pragma unroll
            for (int i = 0; i < 4; i++)
#pragma unroll
                for (int j = 0; j < 4; j++)
                    acc[i][j] = __builtin_amdgcn_mfma_f32_16x16x32_f16(a[i], b[j], acc[i][j], 0, 0, 0);
        }
        __syncthreads();
    }

#pragma unroll
    for (int i = 0; i < 4; i++)
#pragma unroll
        for (int j = 0; j < 4; j++) {
            int n = n0 + wave * 64 + j * 16 + l16;
#pragma unroll
            for (int r = 0; r < 4; r++)
                gates[(size_t)(m0 + i * 16 + u4 * 4 + r) * NGATE + n] = acc[i][j][r];
        }
}

// ---------------- LSTM elementwise + bias + output projection ----------------
__global__ __launch_bounds__(128)
void lstm_kernel(const float* __restrict__ gates, const float* __restrict__ c0,
                 const float* __restrict__ biasv, const float* __restrict__ fc_w,
                 const float* __restrict__ fc_b, float* __restrict__ out) {
    __shared__ float red[2];
    int n = blockIdx.x;
    int o = threadIdx.x;
    const float* g = gates + (size_t)n * NGATE;
    float gi = g[o]          + biasv[o];
    float gf = g[H2 + o]     + biasv[H2 + o];
    float gt = g[2 * H2 + o] + biasv[2 * H2 + o];
    float go = g[3 * H2 + o] + biasv[3 * H2 + o];
    float iv = 1.f / (1.f + expf(-gi));
    float fv = 1.f / (1.f + expf(-gf));
    float tv = tanhf(gt);
    float ov = 1.f / (1.f + expf(-go));
    float c = fv * c0[(size_t)n * H2 + o] + iv * tv;
    float h = ov * tanhf(c);
    out[N_REAL + (size_t)n * H2 + o] = h;

    float r = fmaxf(h, 0.f) * fc_w[o];
#pragma unroll
    for (int s = 32; s; s >>= 1) r += __shfl_down(r, s);
    if ((o & 63) == 0) red[o >> 6] = r;
    __syncthreads();
    if (o == 0 && n < N_REAL) out[n] = red[0] + red[1] + fc_b[0];
}

extern "C" void kernel_launch(void* const* d_in, const int* in_sizes, int n_in,
                              void* d_out, int out_size, void* d_ws, size_t ws_size,
                              hipStream_t stream) {
    const float* x     = (const float*)d_in[0];
    const int*   ei    = (const int*)d_in[1];
    const float* ew    = (const float*)d_in[2];
    const float* h0    = (const float*)d_in[3];
    const float* c0    = (const float*)d_in[4];
    const float* fc0_w = (const float*)d_in[5];
    const float* fc0_b = (const float*)d_in[6];
    const float* Wx    = (const float*)d_in[7];
    const float* bg    = (const float*)d_in[8];
    const float* cw0   = (const float*)d_in[9];
    const float* cw1   = (const float*)d_in[10];
    const float* cb    = (const float*)d_in[11];
    const float* fc_w  = (const float*)d_in[12];
    const float* fc_b  = (const float*)d_in[13];
    float* out = (float*)d_out;

    float* P      = (float*)d_ws;                     // 16*3072*256 f32 = 50.3 MB
    float* gates  = P + (size_t)SPLITK * MPAD * H1;   // 3072*512
    float* biasv  = gates + (size_t)MPAD * NGATE;     // 512
    float* deg    = biasv + NGATE;                    // 3000
    float* dinv   = deg + NPAD;                       // 3000
    int*   counts = (int*)(dinv + NPAD);              // 3072
    int*   offs   = counts + 3072;                    // 3072 (need 3001)
    int*   cursor = offs + 3072;                      // 3072
    int*   eid    = cursor + 3072;                    // NE
    _Float16* U16 = (_Float16*)(((uintptr_t)(eid + NE) + 255) & ~(uintptr_t)255); // 3072*512
    _Float16* Wc  = U16 + (size_t)MPAD * UDIM;        // 512*512
    _Float16* wT  = Wc + (size_t)UDIM * NGATE;        // 256*8192

    hipMemsetAsync(deg, 0, NPAD * sizeof(float), stream);
    hipMemsetAsync(counts, 0, 3072 * sizeof(int), stream);

    prep_kernel<<<3072, 256, 0, stream>>>(fc0_w, Wx, cw0, cw1, bg, cb, wT, Wc, biasv);
    gemm1_fused<<<dim3(MPAD / 64, SPLITK), 256, 0, stream>>>(x, wT, P);
    hist_kernel<<<(NE + 255) / 256, 256, 0, stream>>>(ei, ew, deg, counts);
    scan_kernel<<<1, 1024, 0, stream>>>(counts, offs, deg, dinv, cursor);
    scatter_kernel<<<(NE + 255) / 256, 256, 0, stream>>>(ei, cursor, eid);
    t1epi_kernel<<<NPAD + ZBLK + HBLK, 128, 0, stream>>>(ei, ew, h0, dinv, offs, eid, P, fc0_b, U16);
    gemm2_mfma<<<dim3(NGATE / 256, MPAD / 64), 256, 0, stream>>>(U16, Wc, gates);
    lstm_kernel<<<NPAD, 128, 0, stream>>>(gates, c0, biasv, fc_w, fc_b, out);
}